// Round 15
// baseline (81.962 us; speedup 1.0000x reference)
//
#include <hip/hip_runtime.h>

#define OC 32
#define IC 16
#define HH 128
#define WW 128
#define NB 8
#define RP 130                              // rp = r+1, r in [-1,128]
#define TRIG_DW (NB * RP * WW * IC)         // [n][rp][w][j] j-fastest: 2,129,920
#define A_OFF TRIG_DW
#define A_DW (OC * 48)                      // [oc][m'], m' = kk*16 + j
#define TOTAL_DW (TRIG_DW + A_DW)

typedef __attribute__((ext_vector_type(8))) __bf16 bf16x8;
typedef __attribute__((ext_vector_type(4))) float f32x4;
typedef __attribute__((ext_vector_type(4))) unsigned int u32x4;

#define INV_2PI 0.15915494309189535f

__device__ inline unsigned int pack2bf(float lo, float hi) {
    union { __bf16 h[2]; unsigned int u; } p;
    p.h[0] = (__bf16)lo;
    p.h[1] = (__bf16)hi;
    return p.u;
}

// v_sin/v_cos take REVOLUTIONS, no HW range reduction; fract() is an EXACT
// period reduction in rev units (verified round 13, absmax 0.0625).
__device__ inline void hw_sincos(float rad, float* sn, float* cs) {
    float rev = rad * INV_2PI;
    float fr = rev - floorf(rev);
    *sn = __builtin_amdgcn_sinf(fr);
    *cs = __builtin_amdgcn_cosf(fr);
}

// K-permutation m' = kk*16 + j (kk-major) makes 4-consecutive-m' = 4
// consecutive j at fixed kk => B fragment load is ONE dwordx4 from the
// [n][rp][w][j] table, and Kt == kk. Same permutation applied to A keeps
// the dot product identical (verified convention from round 10).
__global__ void trig_kernel(const float* __restrict__ x,
                            const float* __restrict__ theta,
                            unsigned int* __restrict__ ws) {
    int idx = blockIdx.x * 256 + threadIdx.x;
    if (idx >= TOTAL_DW) return;

    if (idx < TRIG_DW) {
        int j  = idx & 15;
        int w  = (idx >> 4) & (WW - 1);
        int t3 = idx >> 11;                 // n*130 + rp
        int rp = t3 % RP;
        int n  = t3 / RP;
        int r  = rp - 1;
        unsigned int pk = 0x00003F80u;      // (cos,sin)=(1,0): zero-window identity
        if (r >= 0 && r < HH) {
            const float* row = x + ((size_t)(n * IC + j) * HH + r) * WW;
            float c0 = row[w];
            float cm = (w > 0)      ? row[w - 1] : 0.f;
            float cp = (w < WW - 1) ? row[w + 1] : 0.f;
            float s = cm + c0 + cp;
            float sn, cs;
            hw_sincos(s, &sn, &cs);
            pk = pack2bf(cs, sn);
        }
        ws[idx] = pk;                       // lane-fastest = j-fastest: coalesced
    } else {
        int q  = idx - A_OFF;               // q = oc*48 + m'
        int oc = q / 48;
        int mp = q - oc * 48;
        int kk = mp >> 4;
        int j  = mp & 15;
        float th = theta[(oc * j) * 3 + kk];
        float sn, cs;
        hw_sincos(th, &sn, &cs);
        const float inv3 = 1.0f / 3.0f;
        ws[idx] = pack2bf(cs * inv3, -sn * inv3);
    }
}

// D[oc][px] = A(32x96) x B(96x128); px = hrow*64 + wloc (2 h-rows x 64 w).
// All loads dwordx4; B groups of 16 lanes cover 16 consecutive w = 1KB/instr.
__global__ __launch_bounds__(256, 4) void gemm_kernel(
        const unsigned int* __restrict__ ws,
        float* __restrict__ out) {
    const int tx = threadIdx.x;
    const int ty = threadIdx.y;

    const int bid = blockIdx.x;
    const int wbase = (bid & 1) * 64;
    const int hp = (bid >> 1) & 63;
    const int n  = bid >> 7;
    const int h0 = hp * 2;

    const int l15 = tx & 15;
    const int lk  = tx >> 4;

    union U4 { u32x4 v; bf16x8 h; };

    // ---- A fragments: 6x dwordx4 from 6KB L2-hot table ----
    bf16x8 afr[3][2];
#pragma unroll
    for (int Kt = 0; Kt < 3; ++Kt)
#pragma unroll
        for (int Mt = 0; Mt < 2; ++Mt) {
            U4 a;
            a.v = *(const u32x4*)(ws + A_OFF + (l15 + 16 * Mt) * 48 + Kt * 16 + lk * 4);
            afr[Kt][Mt] = a.h;
        }

    // ---- B fragments: 6x dwordx4, fully coalesced ----
    bf16x8 bfr[3][2];
#pragma unroll
    for (int Nt = 0; Nt < 2; ++Nt) {
        int px = ty * 32 + 16 * Nt + l15;
        int hrow = px >> 6;
        int w = wbase + (px & 63);
#pragma unroll
        for (int Kt = 0; Kt < 3; ++Kt) {
            int rp = h0 + hrow + Kt;        // source row r = h+Kt-1, +1 bias
            U4 b;
            b.v = *(const u32x4*)(ws + ((size_t)(n * RP + rp) * WW + w) * 16 + lk * 4);
            bfr[Kt][Nt] = b.h;
        }
    }

    // ---- 12 MFMA ----
    f32x4 acc[2][2];
#pragma unroll
    for (int a = 0; a < 2; ++a)
#pragma unroll
        for (int b = 0; b < 2; ++b) acc[a][b] = (f32x4){0.f, 0.f, 0.f, 0.f};

#pragma unroll
    for (int Kt = 0; Kt < 3; ++Kt)
#pragma unroll
        for (int Mt = 0; Mt < 2; ++Mt)
#pragma unroll
            for (int Nt = 0; Nt < 2; ++Nt)
                acc[Mt][Nt] = __builtin_amdgcn_mfma_f32_16x16x32_bf16(
                    afr[Kt][Mt], bfr[Kt][Nt], acc[Mt][Nt], 0, 0, 0);

    // ---- epilogue (1/3 folded into A): col=l15 -> px, row=lk*4+e -> oc ----
#pragma unroll
    for (int Mt = 0; Mt < 2; ++Mt)
#pragma unroll
        for (int Nt = 0; Nt < 2; ++Nt)
#pragma unroll
            for (int e = 0; e < 4; ++e) {
                int oc = 16 * Mt + lk * 4 + e;
                int px = ty * 32 + 16 * Nt + l15;
                int hrow = px >> 6, wloc = px & 63;
                out[(((size_t)n * OC + oc) * HH + (h0 + hrow)) * WW + (wbase + wloc)]
                    = acc[Mt][Nt][e];
            }
}

extern "C" void kernel_launch(void* const* d_in, const int* in_sizes, int n_in,
                              void* d_out, int out_size, void* d_ws, size_t ws_size,
                              hipStream_t stream) {
    const float* x     = (const float*)d_in[0];
    const float* theta = (const float*)d_in[1];
    float* out = (float*)d_out;
    unsigned int* ws = (unsigned int*)d_ws;

    trig_kernel<<<(TOTAL_DW + 255) / 256, 256, 0, stream>>>(x, theta, ws);

    dim3 block(64, 4, 1);
    gemm_kernel<<<NB * (HH / 2) * 2, block, 0, stream>>>(ws, out);
}

// Round 16
// 75.391 us; speedup vs baseline: 1.0872x; 1.0872x over previous
//
#include <hip/hip_runtime.h>

#define OC 32
#define IC 16
#define HH 128
#define WW 128
#define NB 8
#define RP 130                              // rp = r+1, r in [-1,128]
#define TRIG_DW (NB * RP * WW * IC)         // [n][rp][w][j], j fastest: 2,129,920
#define A_OFF TRIG_DW
#define A_DW (OC * 48)                      // [oc][m'], m' = kk*16 + j
#define TOTAL_DW (TRIG_DW + A_DW)

typedef __attribute__((ext_vector_type(8))) __bf16 bf16x8;
typedef __attribute__((ext_vector_type(4))) float f32x4;
typedef __attribute__((ext_vector_type(4))) unsigned int u32x4;

#define INV_2PI 0.15915494309189535f

__device__ inline unsigned int pack2bf(float lo, float hi) {
    union { __bf16 h[2]; unsigned int u; } p;
    p.h[0] = (__bf16)lo;
    p.h[1] = (__bf16)hi;
    return p.u;
}

// v_sin/v_cos take REVOLUTIONS, no HW range reduction; fract() is an EXACT
// period reduction in rev units (verified round 13, absmax 0.0625).
__device__ inline void hw_sincos(float rad, float* sn, float* cs) {
    float rev = rad * INV_2PI;
    float fr = rev - floorf(rev);
    *sn = __builtin_amdgcn_sinf(fr);
    *cs = __builtin_amdgcn_cosf(fr);
}

// Trig table builder, coalesced on BOTH sides (r15 regression was the
// j-fastest GATHER read: 16 planes @64KB stride per wave).
// Block bid < NB*RP: one (n,rp) row. Read x with w lane-fastest (coalesced),
// transpose through LDS[w][j] (stride 17: conflict-free), write [w][j]
// j-fastest as 2KB-contiguous dwordx4 waves.
__global__ __launch_bounds__(256) void trig_kernel(
        const float* __restrict__ x,
        const float* __restrict__ theta,
        unsigned int* __restrict__ ws) {
    __shared__ unsigned int T[128 * 17];    // 34.8 KB

    const int bid = blockIdx.x;
    const int t = threadIdx.x;

    if (bid == NB * RP) {                   // A-table block (r15-verified code)
        const float inv3 = 1.0f / 3.0f;
        for (int q = t; q < OC * 48; q += 256) {
            int oc = q / 48;
            int mp = q - oc * 48;
            int kk = mp >> 4;
            int j  = mp & 15;
            float th = theta[(oc * j) * 3 + kk];
            float sn, cs;
            hw_sincos(th, &sn, &cs);
            ws[A_OFF + q] = pack2bf(cs * inv3, -sn * inv3);
        }
        return;
    }

    const int n  = bid / RP;
    const int rp = bid - n * RP;
    const int r  = rp - 1;
    unsigned int* dst = ws + (size_t)bid * 2048;   // [w][j] tile, 2048 dwords

    if (r < 0 || r >= HH) {                 // pad row: (cos,sin)=(1,0) identity
        u32x4 v = (u32x4){0x3F80u, 0x3F80u, 0x3F80u, 0x3F80u};
        *(u32x4*)(dst + t * 8)     = v;
        *(u32x4*)(dst + t * 8 + 4) = v;
        return;
    }

    // read phase: w = t&127 lane-fastest; 8 j's per thread
    const int w  = t & 127;
    const int jr = t >> 7;
    const float* xr = x + ((size_t)n * IC * HH + r) * WW;
    const bool wl = (w > 0), wrk = (w < WW - 1);
#pragma unroll
    for (int it = 0; it < 8; ++it) {
        int j = it * 2 + jr;
        const float* row = xr + (size_t)j * (HH * WW);
        float c0 = row[w];
        float cm = wl  ? row[w - 1] : 0.f;
        float cp = wrk ? row[w + 1] : 0.f;
        float s = cm + c0 + cp;
        float sn, cs;
        hw_sincos(s, &sn, &cs);
        T[w * 17 + j] = pack2bf(cs, sn);
    }
    __syncthreads();

    // write phase: q = t*8+e -> j = q&15 fastest, w = q>>4; coalesced dwordx4
    const int wo = t >> 1;
    const int jh = (t & 1) * 8;
    unsigned int vals[8];
#pragma unroll
    for (int e = 0; e < 8; ++e) vals[e] = T[wo * 17 + jh + e];
    *(u32x4*)(dst + t * 8)     = (u32x4){vals[0], vals[1], vals[2], vals[3]};
    *(u32x4*)(dst + t * 8 + 4) = (u32x4){vals[4], vals[5], vals[6], vals[7]};
}

// GEMM kernel: byte-identical to round 15 (verified, absmax 0.0625).
// D[oc][px] = A(32x96) x B(96x128); px = hrow*64 + wloc; all loads dwordx4.
__global__ __launch_bounds__(256, 4) void gemm_kernel(
        const unsigned int* __restrict__ ws,
        float* __restrict__ out) {
    const int tx = threadIdx.x;
    const int ty = threadIdx.y;

    const int bid = blockIdx.x;
    const int wbase = (bid & 1) * 64;
    const int hp = (bid >> 1) & 63;
    const int n  = bid >> 7;
    const int h0 = hp * 2;

    const int l15 = tx & 15;
    const int lk  = tx >> 4;

    union U4 { u32x4 v; bf16x8 h; };

    bf16x8 afr[3][2];
#pragma unroll
    for (int Kt = 0; Kt < 3; ++Kt)
#pragma unroll
        for (int Mt = 0; Mt < 2; ++Mt) {
            U4 a;
            a.v = *(const u32x4*)(ws + A_OFF + (l15 + 16 * Mt) * 48 + Kt * 16 + lk * 4);
            afr[Kt][Mt] = a.h;
        }

    bf16x8 bfr[3][2];
#pragma unroll
    for (int Nt = 0; Nt < 2; ++Nt) {
        int px = ty * 32 + 16 * Nt + l15;
        int hrow = px >> 6;
        int w = wbase + (px & 63);
#pragma unroll
        for (int Kt = 0; Kt < 3; ++Kt) {
            int rp = h0 + hrow + Kt;
            U4 b;
            b.v = *(const u32x4*)(ws + ((size_t)(n * RP + rp) * WW + w) * 16 + lk * 4);
            bfr[Kt][Nt] = b.h;
        }
    }

    f32x4 acc[2][2];
#pragma unroll
    for (int a = 0; a < 2; ++a)
#pragma unroll
        for (int b = 0; b < 2; ++b) acc[a][b] = (f32x4){0.f, 0.f, 0.f, 0.f};

#pragma unroll
    for (int Kt = 0; Kt < 3; ++Kt)
#pragma unroll
        for (int Mt = 0; Mt < 2; ++Mt)
#pragma unroll
            for (int Nt = 0; Nt < 2; ++Nt)
                acc[Mt][Nt] = __builtin_amdgcn_mfma_f32_16x16x32_bf16(
                    afr[Kt][Mt], bfr[Kt][Nt], acc[Mt][Nt], 0, 0, 0);

#pragma unroll
    for (int Mt = 0; Mt < 2; ++Mt)
#pragma unroll
        for (int Nt = 0; Nt < 2; ++Nt)
#pragma unroll
            for (int e = 0; e < 4; ++e) {
                int oc = 16 * Mt + lk * 4 + e;
                int px = ty * 32 + 16 * Nt + l15;
                int hrow = px >> 6, wloc = px & 63;
                out[(((size_t)n * OC + oc) * HH + (h0 + hrow)) * WW + (wbase + wloc)]
                    = acc[Mt][Nt][e];
            }
}

extern "C" void kernel_launch(void* const* d_in, const int* in_sizes, int n_in,
                              void* d_out, int out_size, void* d_ws, size_t ws_size,
                              hipStream_t stream) {
    const float* x     = (const float*)d_in[0];
    const float* theta = (const float*)d_in[1];
    float* out = (float*)d_out;
    unsigned int* ws = (unsigned int*)d_ws;

    trig_kernel<<<NB * RP + 1, 256, 0, stream>>>(x, theta, ws);

    dim3 block(64, 4, 1);
    gemm_kernel<<<NB * (HH / 2) * 2, block, 0, stream>>>(ws, out);
}

// Round 17
// 74.557 us; speedup vs baseline: 1.0993x; 1.0112x over previous
//
#include <hip/hip_runtime.h>

#define OC 32
#define IC 16
#define HH 128
#define WW 128
#define NB 8
#define RP 130                              // rp = r+1, r in [-1,128]
#define TRIG_DW (NB * RP * WW * IC)         // [n][rp][w][j], j fastest: 2,129,920
#define A_OFF TRIG_DW
#define A_DW (OC * 48)                      // [oc][m'], m' = kk*16 + j
#define TOTAL_DW (TRIG_DW + A_DW)

typedef __attribute__((ext_vector_type(8))) __bf16 bf16x8;
typedef __attribute__((ext_vector_type(4))) float f32x4;
typedef __attribute__((ext_vector_type(4))) unsigned int u32x4;

#define INV_2PI 0.15915494309189535f

__device__ inline unsigned int pack2bf(float lo, float hi) {
    union { __bf16 h[2]; unsigned int u; } p;
    p.h[0] = (__bf16)lo;
    p.h[1] = (__bf16)hi;
    return p.u;
}

// v_sin/v_cos take REVOLUTIONS, no HW range reduction; fract() is an EXACT
// period reduction in rev units (verified round 13, absmax 0.0625).
__device__ inline void hw_sincos(float rad, float* sn, float* cs) {
    float rev = rad * INV_2PI;
    float fr = rev - floorf(rev);
    *sn = __builtin_amdgcn_sinf(fr);
    *cs = __builtin_amdgcn_cosf(fr);
}

// Trig builder, fine-grained: 128-thread block = HALF a (n,rp) row (64 w).
// Anti-lockstep: 2081 small blocks, ~16/CU, stagger naturally; serial chain
// per block is short. Same layout/math as round 16 (verified).
__global__ __launch_bounds__(128) void trig_kernel(
        const float* __restrict__ x,
        const float* __restrict__ theta,
        unsigned int* __restrict__ ws) {
    __shared__ unsigned int T[64 * 17];     // 4.6 KB

    const int bid = blockIdx.x;
    const int t = threadIdx.x;

    if (bid == NB * RP * 2) {               // A-table block
        const float inv3 = 1.0f / 3.0f;
        for (int q = t; q < OC * 48; q += 128) {
            int oc = q / 48;
            int mp = q - oc * 48;
            int kk = mp >> 4;
            int j  = mp & 15;
            float th = theta[(oc * j) * 3 + kk];
            float sn, cs;
            hw_sincos(th, &sn, &cs);
            ws[A_OFF + q] = pack2bf(cs * inv3, -sn * inv3);
        }
        return;
    }

    const int half  = bid & 1;
    const int rowid = bid >> 1;             // n*RP + rp
    const int n  = rowid / RP;
    const int rp = rowid - n * RP;
    const int r  = rp - 1;
    unsigned int* dst = ws + (size_t)rowid * 2048 + half * 1024;  // [w][j] halftile

    if (r < 0 || r >= HH) {                 // pad row: (cos,sin)=(1,0) identity
        u32x4 v = (u32x4){0x3F80u, 0x3F80u, 0x3F80u, 0x3F80u};
        *(u32x4*)(dst + t * 8)     = v;
        *(u32x4*)(dst + t * 8 + 4) = v;
        return;
    }

    // read phase: wl = t&63 lane-fastest (coalesced); 8 j's per thread
    const int wl = t & 63;
    const int w  = half * 64 + wl;
    const int jr = t >> 6;                  // 0..1
    const float* xr = x + ((size_t)n * IC * HH + r) * WW;
    const bool wlo = (w > 0), whi = (w < WW - 1);
#pragma unroll
    for (int it = 0; it < 8; ++it) {
        int j = it * 2 + jr;
        const float* row = xr + (size_t)j * (HH * WW);
        float c0 = row[w];
        float cm = wlo ? row[w - 1] : 0.f;
        float cp = whi ? row[w + 1] : 0.f;
        float s = cm + c0 + cp;
        float sn, cs;
        hw_sincos(s, &sn, &cs);
        T[wl * 17 + j] = pack2bf(cs, sn);
    }
    __syncthreads();

    // write phase: q = t*8+e -> j fastest; coalesced dwordx4 (1KB/wave-instr)
    const int wo = t >> 1;
    const int jh = (t & 1) * 8;
    unsigned int vals[8];
#pragma unroll
    for (int e = 0; e < 8; ++e) vals[e] = T[wo * 17 + jh + e];
    *(u32x4*)(dst + t * 8)     = (u32x4){vals[0], vals[1], vals[2], vals[3]};
    *(u32x4*)(dst + t * 8 + 4) = (u32x4){vals[4], vals[5], vals[6], vals[7]};
}

// GEMM, fine-grained: ONE WAVE per block (no barrier), 4096 blocks.
// Each wave = exactly one ty-slice of the round-16 block (verified math).
// D[oc][px] = A(32x96) x B(96x128); px slice of 32 = hrowless w range.
__global__ __launch_bounds__(64, 4) void gemm_kernel(
        const unsigned int* __restrict__ ws,
        float* __restrict__ out) {
    const int tx = threadIdx.x;

    const int bid  = blockIdx.x;
    const int ty   = bid & 3;               // former threadIdx.y
    const int bidp = bid >> 2;
    const int wbase = (bidp & 1) * 64;
    const int hp = (bidp >> 1) & 63;
    const int n  = bidp >> 7;
    const int h0 = hp * 2;

    const int l15 = tx & 15;
    const int lk  = tx >> 4;

    union U4 { u32x4 v; bf16x8 h; };

    // A fragments: 6x dwordx4 from 6KB L2/L3-hot table
    bf16x8 afr[3][2];
#pragma unroll
    for (int Kt = 0; Kt < 3; ++Kt)
#pragma unroll
        for (int Mt = 0; Mt < 2; ++Mt) {
            U4 a;
            a.v = *(const u32x4*)(ws + A_OFF + (l15 + 16 * Mt) * 48 + Kt * 16 + lk * 4);
            afr[Kt][Mt] = a.h;
        }

    // B fragments: 6x dwordx4, coalesced (16 lanes = 16 consecutive w)
    bf16x8 bfr[3][2];
#pragma unroll
    for (int Nt = 0; Nt < 2; ++Nt) {
        int px = ty * 32 + 16 * Nt + l15;
        int hrow = px >> 6;
        int w = wbase + (px & 63);
#pragma unroll
        for (int Kt = 0; Kt < 3; ++Kt) {
            int rp = h0 + hrow + Kt;
            U4 b;
            b.v = *(const u32x4*)(ws + ((size_t)(n * RP + rp) * WW + w) * 16 + lk * 4);
            bfr[Kt][Nt] = b.h;
        }
    }

    f32x4 acc[2][2];
#pragma unroll
    for (int a = 0; a < 2; ++a)
#pragma unroll
        for (int b = 0; b < 2; ++b) acc[a][b] = (f32x4){0.f, 0.f, 0.f, 0.f};

#pragma unroll
    for (int Kt = 0; Kt < 3; ++Kt)
#pragma unroll
        for (int Mt = 0; Mt < 2; ++Mt)
#pragma unroll
            for (int Nt = 0; Nt < 2; ++Nt)
                acc[Mt][Nt] = __builtin_amdgcn_mfma_f32_16x16x32_bf16(
                    afr[Kt][Mt], bfr[Kt][Nt], acc[Mt][Nt], 0, 0, 0);

    // epilogue (1/3 folded into A): col=l15 -> px, row=lk*4+e -> oc
#pragma unroll
    for (int Mt = 0; Mt < 2; ++Mt)
#pragma unroll
        for (int Nt = 0; Nt < 2; ++Nt)
#pragma unroll
            for (int e = 0; e < 4; ++e) {
                int oc = 16 * Mt + lk * 4 + e;
                int px = ty * 32 + 16 * Nt + l15;
                int hrow = px >> 6, wloc = px & 63;
                out[(((size_t)n * OC + oc) * HH + (h0 + hrow)) * WW + (wbase + wloc)]
                    = acc[Mt][Nt][e];
            }
}

extern "C" void kernel_launch(void* const* d_in, const int* in_sizes, int n_in,
                              void* d_out, int out_size, void* d_ws, size_t ws_size,
                              hipStream_t stream) {
    const float* x     = (const float*)d_in[0];
    const float* theta = (const float*)d_in[1];
    float* out = (float*)d_out;
    unsigned int* ws = (unsigned int*)d_ws;

    trig_kernel<<<NB * RP * 2 + 1, 128, 0, stream>>>(x, theta, ws);

    gemm_kernel<<<NB * (HH / 2) * 2 * 4, 64, 0, stream>>>(ws, out);
}